// Round 3
// baseline (343.406 us; speedup 1.0000x reference)
//
#include <hip/hip_runtime.h>

// Quantize/dequantize with 64-level sorted codebook (L=64).
//   r = x - means
//   pos = clip(searchsorted(cb, r), 1, 63)           // side='left'
//   sym = (r - cb[pos-1] <= cb[pos] - r) ? pos-1 : pos
//   y_hat = cb[sym] + means
// FP ops replicate the JAX reference exactly -> absmax 0.
//
// Memory-bound: 402 MB total traffic, floor ~64 us @ 6.3 TB/s.
// Each thread handles 2 float4s (ILP across the two serial LDS search chains).
// LDS search: step-k index set aliases <=2 lanes/bank (free on gfx950, m136).
// Stores are nontemporal (write-once output, keep out of L2).
// NOTE: __builtin_nontemporal_* requires clang ext_vector_type, not HIP float4.

typedef float v4f __attribute__((ext_vector_type(4)));

__device__ __forceinline__ void nearest(const float* __restrict__ s_cb,
                                        float r, float m,
                                        float& sym, float& y)
{
    // branchless lower_bound: p = #{ j : cb[j] < r }
    int p = 0;
#pragma unroll
    for (int s = 32; s > 0; s >>= 1) {
        p += (s_cb[p + s - 1] < r) ? s : 0;
    }
    p = min(max(p, 1), 63);
    const float left  = s_cb[p - 1];
    const float right = s_cb[p];
    const int idx = ((r - left) <= (right - r)) ? (p - 1) : p;
    sym = (float)idx;
    y   = s_cb[idx] + m;
}

__global__ __launch_bounds__(256) void quant_dequant_kernel(
    const v4f* __restrict__ x4,
    const v4f* __restrict__ m4,
    const float* __restrict__ codebook,
    v4f* __restrict__ sym_out,   // symbols as float values
    v4f* __restrict__ yhat_out,
    int n8)                      // n/8
{
    __shared__ float s_cb[64];
    if (threadIdx.x < 64) s_cb[threadIdx.x] = codebook[threadIdx.x];
    __syncthreads();

    const int i = blockIdx.x * blockDim.x + threadIdx.x;
    if (i >= n8) return;
    const int j = i + n8;

    // issue all global loads up front
    const v4f xa = x4[i];
    const v4f ma = m4[i];
    const v4f xb = x4[j];
    const v4f mb = m4[j];

    v4f sa, ya, sb, yb;
#pragma unroll
    for (int k = 0; k < 4; ++k) {
        float s0, y0, s1, y1;
        nearest(s_cb, xa[k] - ma[k], ma[k], s0, y0);
        nearest(s_cb, xb[k] - mb[k], mb[k], s1, y1);
        sa[k] = s0; ya[k] = y0;
        sb[k] = s1; yb[k] = y1;
    }

    __builtin_nontemporal_store(sa, &sym_out[i]);
    __builtin_nontemporal_store(ya, &yhat_out[i]);
    __builtin_nontemporal_store(sb, &sym_out[j]);
    __builtin_nontemporal_store(yb, &yhat_out[j]);
}

extern "C" void kernel_launch(void* const* d_in, const int* in_sizes, int n_in,
                              void* d_out, int out_size, void* d_ws, size_t ws_size,
                              hipStream_t stream)
{
    const float* x     = (const float*)d_in[0];
    const float* means = (const float*)d_in[1];
    const float* cb    = (const float*)d_in[2];

    const int n  = in_sizes[0];      // 25,165,824
    const int n8 = n / 8;            // 3,145,728

    float* out = (float*)d_out;      // [0..n): symbols (as float), [n..2n): y_hat

    const int block = 256;
    const int grid  = (n8 + block - 1) / block;   // 12288

    quant_dequant_kernel<<<grid, block, 0, stream>>>(
        (const v4f*)x, (const v4f*)means, cb,
        (v4f*)out, (v4f*)(out + n), n8);
}